// Round 4
// baseline (5456.406 us; speedup 1.0000x reference)
//
#include <hip/hip_runtime.h>
#include <stdint.h>

#define NN 4096
#define BB 4
#define RPB 16          // rows per block
#define TPB 1024

// ---------- bf16 round-to-nearest-even ----------
__device__ __forceinline__ uint32_t bf16rne(float f) {
  uint32_t u = __float_as_uint(f);
  return (u + 0x7FFFu + ((u >> 16) & 1u)) >> 16;
}

// ---------- pack B_real/B_imag (f32) -> bf16 pair per u32 ----------
__global__ void pack_kernel(const float* __restrict__ Br, const float* __restrict__ Bi,
                            uint32_t* __restrict__ Bp) {
  int i = blockIdx.x * blockDim.x + threadIdx.x;   // over N*N/4
  float4 r = reinterpret_cast<const float4*>(Br)[i];
  float4 m = reinterpret_cast<const float4*>(Bi)[i];
  uint4 o;
  o.x = bf16rne(r.x) | (bf16rne(m.x) << 16);
  o.y = bf16rne(r.y) | (bf16rne(m.y) << 16);
  o.z = bf16rne(r.z) | (bf16rne(m.z) << 16);
  o.w = bf16rne(r.w) | (bf16rne(m.w) << 16);
  reinterpret_cast<uint4*>(Bp)[i] = o;
}

// ---------- x0 = exp(i*theta): state (complex interleaved) + out real plane t=0 ----------
__global__ void init_kernel(const float* __restrict__ ang,
                            float2* __restrict__ st0, float* __restrict__ out0) {
  int i = blockIdx.x * blockDim.x + threadIdx.x;
  if (i < BB * NN) {
    float s, c;
    sincosf(ang[i], &s, &c);
    st0[i] = make_float2(c, s);
    out0[i] = c;
  }
}

// ---------- one recurrence step ----------
// state [b][n] complex interleaved (float2); d_out gets REAL part only, [t][b][n]
// LDS: xl[n][4] = {r0,i0,r1,i1}, xh[n][4] = {r2,i2,r3,i3}, red[16][32]
template <bool PACKED>
__global__ __launch_bounds__(TPB)
void step_kernel(const uint32_t* __restrict__ Bp,
                 const float* __restrict__ Brf,
                 const float* __restrict__ Bif,
                 const float* __restrict__ omega,
                 const float2* __restrict__ stPrev,
                 float2* __restrict__ stNext,
                 float* __restrict__ outRe) {
  extern __shared__ float lds[];
  float* xl  = lds;                // 4096*4 f32 = 64 KB
  float* xh  = lds + NN * 4;       // 64 KB
  float* red = lds + NN * 8;       // 2 KB

  const int tid = threadIdx.x;

  // ---- stage x_t into LDS ----
#pragma unroll
  for (int k = 0; k < 16; ++k) {
    int idx = tid + k * TPB;             // [b][n] flat
    int b = idx >> 12;
    int n = idx & (NN - 1);
    float2 v = stPrev[idx];
    float* dst = (b < 2) ? xl : xh;
    reinterpret_cast<float2*>(dst)[n * 2 + (b & 1)] = v;
  }
  __syncthreads();

  const int w    = tid >> 6;
  const int lane = tid & 63;
  const int rg   = w >> 2;             // row group (4 rows)
  const int q    = w & 3;              // n-quarter
  const int row0 = blockIdx.x * RPB + rg * 4;

  float acc[4][8];
#pragma unroll
  for (int r = 0; r < 4; ++r)
#pragma unroll
    for (int c = 0; c < 8; ++c) acc[r][c] = 0.0f;

#define CFMA(A, BR, BI, XA, XB)                                   \
  A[0] = fmaf(BR, XA.x, A[0]); A[0] = fmaf(-BI, XA.y, A[0]);      \
  A[1] = fmaf(BR, XA.y, A[1]); A[1] = fmaf(BI, XA.x, A[1]);       \
  A[2] = fmaf(BR, XA.z, A[2]); A[2] = fmaf(-BI, XA.w, A[2]);      \
  A[3] = fmaf(BR, XA.w, A[3]); A[3] = fmaf(BI, XA.z, A[3]);       \
  A[4] = fmaf(BR, XB.x, A[4]); A[4] = fmaf(-BI, XB.y, A[4]);      \
  A[5] = fmaf(BR, XB.y, A[5]); A[5] = fmaf(BI, XB.x, A[5]);       \
  A[6] = fmaf(BR, XB.z, A[6]); A[6] = fmaf(-BI, XB.w, A[6]);      \
  A[7] = fmaf(BR, XB.w, A[7]); A[7] = fmaf(BI, XB.z, A[7]);

  if (PACKED) {
    const uint4* pr[4];
#pragma unroll
    for (int r = 0; r < 4; ++r)
      pr[r] = reinterpret_cast<const uint4*>(Bp + (size_t)(row0 + r) * NN + q * 1024);
#pragma unroll
    for (int i4 = 0; i4 < 4; ++i4) {
      const int n0 = q * 1024 + i4 * 256 + lane * 4;
      float4 xa[4], xb[4];
#pragma unroll
      for (int j = 0; j < 4; ++j) {
        xa[j] = reinterpret_cast<const float4*>(xl)[n0 + j];
        xb[j] = reinterpret_cast<const float4*>(xh)[n0 + j];
      }
#pragma unroll
      for (int r = 0; r < 4; ++r) {
        uint4 pv = pr[r][i4 * 64 + lane];
        float* a = acc[r];
        uint32_t u;
        u = pv.x; { float br = __uint_as_float(u << 16), bi = __uint_as_float(u & 0xFFFF0000u); CFMA(a, br, bi, xa[0], xb[0]); }
        u = pv.y; { float br = __uint_as_float(u << 16), bi = __uint_as_float(u & 0xFFFF0000u); CFMA(a, br, bi, xa[1], xb[1]); }
        u = pv.z; { float br = __uint_as_float(u << 16), bi = __uint_as_float(u & 0xFFFF0000u); CFMA(a, br, bi, xa[2], xb[2]); }
        u = pv.w; { float br = __uint_as_float(u << 16), bi = __uint_as_float(u & 0xFFFF0000u); CFMA(a, br, bi, xa[3], xb[3]); }
      }
    }
  } else {
    const float4* rr[4];
    const float4* ir[4];
#pragma unroll
    for (int r = 0; r < 4; ++r) {
      rr[r] = reinterpret_cast<const float4*>(Brf + (size_t)(row0 + r) * NN + q * 1024);
      ir[r] = reinterpret_cast<const float4*>(Bif + (size_t)(row0 + r) * NN + q * 1024);
    }
#pragma unroll
    for (int i4 = 0; i4 < 4; ++i4) {
      const int n0 = q * 1024 + i4 * 256 + lane * 4;
      float4 xa[4], xb[4];
#pragma unroll
      for (int j = 0; j < 4; ++j) {
        xa[j] = reinterpret_cast<const float4*>(xl)[n0 + j];
        xb[j] = reinterpret_cast<const float4*>(xh)[n0 + j];
      }
#pragma unroll
      for (int r = 0; r < 4; ++r) {
        float4 pvr = rr[r][i4 * 64 + lane];
        float4 pvi = ir[r][i4 * 64 + lane];
        float* a = acc[r];
        CFMA(a, pvr.x, pvi.x, xa[0], xb[0]);
        CFMA(a, pvr.y, pvi.y, xa[1], xb[1]);
        CFMA(a, pvr.z, pvi.z, xa[2], xb[2]);
        CFMA(a, pvr.w, pvi.w, xa[3], xb[3]);
      }
    }
  }
#undef CFMA

  // ---- in-wave butterfly reduction over 64 lanes ----
#pragma unroll
  for (int r = 0; r < 4; ++r) {
#pragma unroll
    for (int c = 0; c < 8; ++c) {
      float v = acc[r][c];
      v += __shfl_xor(v, 32, 64);
      v += __shfl_xor(v, 16, 64);
      v += __shfl_xor(v, 8, 64);
      v += __shfl_xor(v, 4, 64);
      v += __shfl_xor(v, 2, 64);
      v += __shfl_xor(v, 1, 64);
      acc[r][c] = v;
    }
  }
  if (lane == 0) {
#pragma unroll
    for (int r = 0; r < 4; ++r)
#pragma unroll
      for (int c = 0; c < 8; ++c) red[w * 32 + r * 8 + c] = acc[r][c];
  }
  __syncthreads();

  // ---- cross-wave sum + diagonal term + writes ----
  if (tid < 128) {
    int rg2 = tid >> 5;
    int v   = tid & 31;
    float s = red[(rg2 * 4 + 0) * 32 + v] + red[(rg2 * 4 + 1) * 32 + v] +
              red[(rg2 * 4 + 2) * 32 + v] + red[(rg2 * 4 + 3) * 32 + v];
    int r  = v >> 3;
    int c  = v & 7;
    int b  = c >> 1;
    int ri = c & 1;
    int m  = blockIdx.x * RPB + rg2 * 4 + r;
    float om = omega[b * NN + m];
    const float* xs = (b < 2) ? xl : xh;
    float xr = xs[m * 4 + (b & 1) * 2];
    float xi = xs[m * 4 + (b & 1) * 2 + 1];
    // i*omega*(xr + i*xi) = -omega*xi + i*omega*xr
    s += (ri == 0) ? (-om * xi) : (om * xr);
    reinterpret_cast<float*>(stNext)[(b * NN + m) * 2 + ri] = s;
    if (ri == 0) outRe[b * NN + m] = s;      // d_out = REAL part only
  }
}

// ---------- host ----------
extern "C" void kernel_launch(void* const* d_in, const int* in_sizes, int n_in,
                              void* d_out, int out_size, void* d_ws, size_t ws_size,
                              hipStream_t stream) {
  const float* B_real = (const float*)d_in[0];
  const float* B_imag = (const float*)d_in[1];
  const float* omega  = (const float*)d_in[2];
  const float* ang    = (const float*)d_in[3];
  float* out = (float*)d_out;

  const int NT = out_size / (BB * NN);                      // 256 (real plane [t][b][n])
  const size_t packBytes = (size_t)NN * NN * sizeof(uint32_t);   // 67 MB
  const size_t stBytes   = (size_t)2 * BB * NN * sizeof(float2); // 256 KB
  const bool packed = ws_size >= packBytes + stBytes;

  uint32_t* Bp;
  float2* st;
  if (packed) {
    Bp = (uint32_t*)d_ws;
    st = (float2*)((char*)d_ws + packBytes);
  } else {
    Bp = nullptr;
    st = (float2*)d_ws;                                     // needs 256 KB
  }
  float2* st0 = st;
  float2* st1 = st + BB * NN;

  const size_t shmem = (size_t)(NN * 8 + 16 * 32) * sizeof(float);  // 133120 B
  (void)hipFuncSetAttribute((const void*)&step_kernel<true>,
                            hipFuncAttributeMaxDynamicSharedMemorySize, (int)shmem);
  (void)hipFuncSetAttribute((const void*)&step_kernel<false>,
                            hipFuncAttributeMaxDynamicSharedMemorySize, (int)shmem);

  if (packed) {
    pack_kernel<<<NN * NN / 4 / 256, 256, 0, stream>>>(B_real, B_imag, Bp);
  }
  init_kernel<<<(BB * NN + 255) / 256, 256, 0, stream>>>(ang, st0, out);

  for (int t = 1; t < NT; ++t) {
    float2* sp = ((t - 1) & 1) ? st1 : st0;
    float2* sn = (t & 1) ? st1 : st0;
    float* outT = out + (size_t)t * BB * NN;
    if (packed) {
      step_kernel<true><<<NN / RPB, TPB, shmem, stream>>>(
          Bp, nullptr, nullptr, omega, sp, sn, outT);
    } else {
      step_kernel<false><<<NN / RPB, TPB, shmem, stream>>>(
          nullptr, B_real, B_imag, omega, sp, sn, outT);
    }
  }
}